// Round 9
// baseline (77.074 us; speedup 1.0000x reference)
//
#include <hip/hip_runtime.h>

// ---------------------------------------------------------------------------
// GMNLayer round 9: single-kernel launch (prep folded in).
//  - Weight B-frags loaded per wave per phase directly from f32 arrays:
//    per frag 1 base + 8 global_load_dword offset:j*256 (L2-hot), cvt->bf16.
//  - 3-phase stick wave (round 8): layer1 x4 tiles -> LDS, layer2 x4,
//    cv/av x4 + full-wave epilogue. Peak VGPR ~128, no __syncthreads.
//  - g1 (s-MLP constant) computed wave-parallel.
// ---------------------------------------------------------------------------

typedef __bf16 bf16x8 __attribute__((ext_vector_type(8)));
typedef float f32x4 __attribute__((ext_vector_type(4)));
typedef float v4f __attribute__((ext_vector_type(4)));

#define UNROLL _Pragma("unroll")

__device__ __forceinline__ bf16x8 cvt_frag(v4f lo, v4f hi) {
    bf16x8 f;
    UNROLL for (int j = 0; j < 4; ++j) { f[j] = (__bf16)lo[j]; f[j + 4] = (__bf16)hi[j]; }
    return f;
}

// B-frags for W row-major [k=64][n=64], frag (nt,kb):
// lane l supplies col nt*16+(l&15), k = kb*32 + (l>>4)*8 + j
__device__ __forceinline__ void load_wfrags_f32(const float* __restrict__ W,
                                                int lane, bf16x8 out[4][2]) {
    const int n0 = lane & 15;
    const int k8 = (lane >> 4) << 3;
    UNROLL for (int nt = 0; nt < 4; ++nt)
        UNROLL for (int kb = 0; kb < 2; ++kb) {
            const float* p = W + (size_t)(kb * 32 + k8) * 64 + nt * 16 + n0;
            bf16x8 f;
            UNROLL for (int j = 0; j < 8; ++j)
                f[j] = (__bf16)p[(size_t)j * 64];
            out[nt][kb] = f;
        }
}

__device__ __forceinline__ void load_raw(v4f r[8], const float* h1p, const float* h2p, int lane) {
    const int o8 = (lane >> 4) << 3;
    r[0] = *(const v4f*)(h1p + o8);      r[1] = *(const v4f*)(h1p + o8 + 4);
    r[2] = *(const v4f*)(h1p + 32 + o8); r[3] = *(const v4f*)(h1p + 32 + o8 + 4);
    r[4] = *(const v4f*)(h2p + o8);      r[5] = *(const v4f*)(h2p + o8 + 4);
    r[6] = *(const v4f*)(h2p + 32 + o8); r[7] = *(const v4f*)(h2p + 32 + o8 + 4);
}

// ---- phase helpers (per-wave LDS tile buffers, no block barrier) ----
__device__ __forceinline__ void l1_tile(const v4f raw[8], int lane,
                                        const bf16x8 bW[4][2], const float cb1v[4],
                                        __bf16* srow)
{
    const int n0 = lane & 15;
    const int g4 = (lane >> 4) << 2;
    bf16x8 a1[2], a2[2];
    a1[0] = cvt_frag(raw[0], raw[1]); a1[1] = cvt_frag(raw[2], raw[3]);
    a2[0] = cvt_frag(raw[4], raw[5]); a2[1] = cvt_frag(raw[6], raw[7]);
    UNROLL for (int nt = 0; nt < 4; ++nt) {
        f32x4 cA = {0.f, 0.f, 0.f, 0.f}, cB = {0.f, 0.f, 0.f, 0.f};
        UNROLL for (int kb = 0; kb < 2; ++kb) {
            cA = __builtin_amdgcn_mfma_f32_16x16x32_bf16(a1[kb], bW[nt][kb], cA, 0, 0, 0);
            cB = __builtin_amdgcn_mfma_f32_16x16x32_bf16(a2[kb], bW[nt][kb], cB, 0, 0, 0);
        }
        UNROLL for (int q = 0; q < 4; ++q) {
            const float v = fmaxf(cA[q] + cb1v[nt], 0.f) + fmaxf(cB[q] + cb1v[nt], 0.f);
            srow[(g4 + q) * 72 + nt * 16 + n0] = (__bf16)v;
        }
    }
}

__device__ __forceinline__ void l2_tile(int lane, const bf16x8 bW[4][2],
                                        const float cb2v[4], __bf16* srow)
{
    const int n0 = lane & 15;
    const int g4 = (lane >> 4) << 2;
    const int kb8 = (lane >> 4) << 3;
    bf16x8 sA[2];
    UNROLL for (int kb = 0; kb < 2; ++kb)
        sA[kb] = *(const bf16x8*)&srow[n0 * 72 + kb * 32 + kb8];
    UNROLL for (int nt = 0; nt < 4; ++nt) {
        f32x4 c = {0.f, 0.f, 0.f, 0.f};
        UNROLL for (int kb = 0; kb < 2; ++kb)
            c = __builtin_amdgcn_mfma_f32_16x16x32_bf16(sA[kb], bW[nt][kb], c, 0, 0, 0);
        UNROLL for (int q = 0; q < 4; ++q)
            srow[(g4 + q) * 72 + nt * 16 + n0] = (__bf16)(c[q] + cb2v[nt]);
    }
}

__device__ __forceinline__ void cvav_tile(int lane,
                                          const bf16x8 bCV[4][2], const bf16x8 bAV[4][2],
                                          const float cvb1v[4], const float avb1v[4],
                                          const float cvw2v[4], const float avw2v[4],
                                          float cvb2s, float avb2s,
                                          const __bf16* srow, float& scv, float& sav)
{
    const int n0 = lane & 15;
    const int kb8 = (lane >> 4) << 3;
    bf16x8 hA[2];
    UNROLL for (int kb = 0; kb < 2; ++kb)
        hA[kb] = *(const bf16x8*)&srow[n0 * 72 + kb * 32 + kb8];
    float pc[4] = {0.f, 0.f, 0.f, 0.f}, pa[4] = {0.f, 0.f, 0.f, 0.f};
    UNROLL for (int nt = 0; nt < 4; ++nt) {
        f32x4 cv = {0.f, 0.f, 0.f, 0.f}, av = {0.f, 0.f, 0.f, 0.f};
        UNROLL for (int kb = 0; kb < 2; ++kb) {
            cv = __builtin_amdgcn_mfma_f32_16x16x32_bf16(hA[kb], bCV[nt][kb], cv, 0, 0, 0);
            av = __builtin_amdgcn_mfma_f32_16x16x32_bf16(hA[kb], bAV[nt][kb], av, 0, 0, 0);
        }
        UNROLL for (int q = 0; q < 4; ++q) {
            pc[q] = fmaf(fmaxf(cv[q] + cvb1v[nt], 0.f), cvw2v[nt], pc[q]);
            pa[q] = fmaf(fmaxf(av[q] + avb1v[nt], 0.f), avw2v[nt], pa[q]);
        }
    }
    UNROLL for (int q = 0; q < 4; ++q)
        UNROLL for (int off = 1; off < 16; off <<= 1) {
            pc[q] += __shfl_xor(pc[q], off, 64);
            pa[q] += __shfl_xor(pa[q], off, 64);
        }
    const int srcl = ((lane & 15) >> 2) << 4;
    const float c0 = __shfl(pc[0], srcl, 64), c1 = __shfl(pc[1], srcl, 64);
    const float c2 = __shfl(pc[2], srcl, 64), c3 = __shfl(pc[3], srcl, 64);
    const float b0 = __shfl(pa[0], srcl, 64), b1 = __shfl(pa[1], srcl, 64);
    const float b2 = __shfl(pa[2], srcl, 64), b3 = __shfl(pa[3], srcl, 64);
    const int qq = lane & 3;
    scv = (qq == 0 ? c0 : qq == 1 ? c1 : qq == 2 ? c2 : c3) + cvb2s;
    sav = (qq == 0 ? b0 : qq == 1 ? b1 : qq == 2 ? b2 : b3) + avb2s;
}

// iso 16-node tile
__device__ __forceinline__ float iso_tile(
    const v4f raw[4], int lane, const bf16x8 bW[4][2],
    const float cvb1v[4], const float cvw2v[4], float cvb2s)
{
    bf16x8 a[2];
    a[0] = cvt_frag(raw[0], raw[1]);
    a[1] = cvt_frag(raw[2], raw[3]);
    float p[4] = {0.f, 0.f, 0.f, 0.f};
    UNROLL for (int nt = 0; nt < 4; ++nt) {
        f32x4 c = {0.f, 0.f, 0.f, 0.f};
        UNROLL for (int kb = 0; kb < 2; ++kb)
            c = __builtin_amdgcn_mfma_f32_16x16x32_bf16(a[kb], bW[nt][kb], c, 0, 0, 0);
        UNROLL for (int q = 0; q < 4; ++q)
            p[q] = fmaf(fmaxf(c[q] + cvb1v[nt], 0.f), cvw2v[nt], p[q]);
    }
    UNROLL for (int q = 0; q < 4; ++q)
        UNROLL for (int off = 1; off < 16; off <<= 1)
            p[q] += __shfl_xor(p[q], off, 64);
    const int srcl = ((lane & 15) >> 2) << 4;
    const float t0 = __shfl(p[0], srcl, 64), t1 = __shfl(p[1], srcl, 64);
    const float t2 = __shfl(p[2], srcl, 64), t3 = __shfl(p[3], srcl, 64);
    const int qq = lane & 3;
    return (qq == 0 ? t0 : qq == 1 ? t1 : qq == 2 ? t2 : t3) + cvb2s;
}

// ------------------------------ fused kernel -------------------------------
__global__ __launch_bounds__(256, 2) void fused_kernel(
    const float* __restrict__ node_feat, const float* __restrict__ node_pos,
    const float* __restrict__ velocity, const float* __restrict__ force,
    const int* __restrict__ iso, const int* __restrict__ stick,
    const float* __restrict__ cvw1, const float* __restrict__ cvb1,
    const float* __restrict__ cvw2, const float* __restrict__ cvb2,
    const float* __restrict__ avw1, const float* __restrict__ avb1,
    const float* __restrict__ avw2, const float* __restrict__ avb2,
    const float* __restrict__ cw1,  const float* __restrict__ cb1,
    const float* __restrict__ cw2,  const float* __restrict__ cb2,
    const float* __restrict__ sw1,  const float* __restrict__ sb1,
    const float* __restrict__ sw2,  const float* __restrict__ sb2,
    float* __restrict__ out_pos, float* __restrict__ out_vel,
    int I, int K, int nStickBlk)
{
    __shared__ __align__(16) __bf16 sbuf[4][4][16 * 72];  // [wave][tile][16x72]
    const int lane = threadIdx.x & 63;
    const int w = threadIdx.x >> 6;
    const int n0 = lane & 15;

    if (blockIdx.x < (unsigned)nStickBlk) {
        // ================= stick path (3-phase) =================
        const int macro = blockIdx.x * 4 + w;
        const int nmacro = (K + 63) >> 6;
        if (macro >= nmacro) return;
        const int base = macro << 6;

        // tile indices (clamped)
        const int s0i = base + n0, s1i = base + 16 + n0;
        const int s2i = base + 32 + n0, s3i = base + 48 + n0;
        const int a0 = (s0i < K) ? s0i : (K - 1), a1i = (s1i < K) ? s1i : (K - 1);
        const int a2i = (s2i < K) ? s2i : (K - 1), a3 = (s3i < K) ? s3i : (K - 1);
        const int t0i1 = stick[a0],  t0i2 = stick[K + a0];
        const int t1i1 = stick[a1i], t1i2 = stick[K + a1i];
        const int t2i1 = stick[a2i], t2i2 = stick[K + a2i];
        const int t3i1 = stick[a3],  t3i2 = stick[K + a3];

        __bf16* srow0 = &sbuf[w][0][0];
        __bf16* srow1 = &sbuf[w][1][0];
        __bf16* srow2 = &sbuf[w][2][0];
        __bf16* srow3 = &sbuf[w][3][0];

        bf16x8 bW[4][2], bW2[4][2];

        // ---------- phase 1: layer-1 for 4 tiles (only cw1 live) ----------
        float cb1v[4];
        UNROLL for (int nt = 0; nt < 4; ++nt) cb1v[nt] = cb1[nt * 16 + n0];
        load_wfrags_f32(cw1, lane, bW);

        v4f rA[8], rB[8];
        load_raw(rA, node_feat + (size_t)t0i1 * 64, node_feat + (size_t)t0i2 * 64, lane);
        load_raw(rB, node_feat + (size_t)t1i1 * 64, node_feat + (size_t)t1i2 * 64, lane);
        l1_tile(rA, lane, bW, cb1v, srow0);
        load_raw(rA, node_feat + (size_t)t2i1 * 64, node_feat + (size_t)t2i2 * 64, lane);
        l1_tile(rB, lane, bW, cb1v, srow1);
        load_raw(rB, node_feat + (size_t)t3i1 * 64, node_feat + (size_t)t3i2 * 64, lane);
        l1_tile(rA, lane, bW, cb1v, srow2);
        l1_tile(rB, lane, bW, cb1v, srow3);

        // ---------- phase 2: layer-2 for 4 tiles (only cw2 live) ----------
        float cb2v[4];
        UNROLL for (int nt = 0; nt < 4; ++nt) cb2v[nt] = 2.0f * cb2[nt * 16 + n0];
        load_wfrags_f32(cw2, lane, bW);
        l2_tile(lane, bW, cb2v, srow0);
        l2_tile(lane, bW, cb2v, srow1);
        l2_tile(lane, bW, cb2v, srow2);
        l2_tile(lane, bW, cb2v, srow3);

        // ---------- phase 3: cv/av for 4 tiles + epilogue gathers ----------
        const int ke = base + lane;
        const bool evalid = ke < K;
        const int kc = evalid ? ke : (K - 1);
        const int i1e = stick[kc];
        const int i2e = stick[K + kc];
        const size_t q1 = (size_t)i1e * 3, q2 = (size_t)i2e * 3;
        const float x1x = node_pos[q1], x1y = node_pos[q1 + 1], x1z = node_pos[q1 + 2];
        const float x2x = node_pos[q2], x2y = node_pos[q2 + 1], x2z = node_pos[q2 + 2];
        const float v1x = velocity[q1], v1y = velocity[q1 + 1], v1z = velocity[q1 + 2];
        const float v2x = velocity[q2], v2y = velocity[q2 + 1], v2z = velocity[q2 + 2];
        const float f1x = force[q1],   f1y = force[q1 + 1],   f1z = force[q1 + 2];
        const float f2x = force[q2],   f2y = force[q2 + 1],   f2z = force[q2 + 2];

        float cvb1v[4], avb1v[4], cvw2v[4], avw2v[4];
        UNROLL for (int nt = 0; nt < 4; ++nt) {
            const int c = nt * 16 + n0;
            cvb1v[nt] = cvb1[c];
            avb1v[nt] = avb1[c];
            cvw2v[nt] = cvw2[c];
            avw2v[nt] = avw2[c];
        }
        const float cvb2s = cvb2[0], avb2s = avb2[0], sb2s = sb2[0];

        // g1 = s-MLP(1.0), wave-parallel
        float gt = fmaxf(sw1[lane] + sb1[lane], 0.f) * sw2[lane];
        UNROLL for (int off = 1; off < 64; off <<= 1)
            gt += __shfl_xor(gt, off, 64);
        const float g1 = gt + sb2s;

        load_wfrags_f32(cvw1, lane, bW);
        load_wfrags_f32(avw1, lane, bW2);
        float scv0, sav0, scv1, sav1, scv2, sav2, scv3, sav3;
        cvav_tile(lane, bW, bW2, cvb1v, avb1v, cvw2v, avw2v, cvb2s, avb2s, srow0, scv0, sav0);
        cvav_tile(lane, bW, bW2, cvb1v, avb1v, cvw2v, avw2v, cvb2s, avb2s, srow1, scv1, sav1);
        cvav_tile(lane, bW, bW2, cvb1v, avb1v, cvw2v, avw2v, cvb2s, avb2s, srow2, scv2, sav2);
        cvav_tile(lane, bW, bW2, cvb1v, avb1v, cvw2v, avw2v, cvb2s, avb2s, srow3, scv3, sav3);

        // redistribute scv/sav to stick-owning lane (stick = base + lane)
        const int T = lane >> 4, r15 = lane & 15;
        const float e0 = __shfl(scv0, r15, 64), e1 = __shfl(scv1, r15, 64);
        const float e2 = __shfl(scv2, r15, 64), e3 = __shfl(scv3, r15, 64);
        const float u0 = __shfl(sav0, r15, 64), u1 = __shfl(sav1, r15, 64);
        const float u2 = __shfl(sav2, r15, 64), u3 = __shfl(sav3, r15, 64);
        const float scv = (T == 0) ? e0 : (T == 1) ? e1 : (T == 2) ? e2 : e3;
        const float sav = (T == 0) ? u0 : (T == 1) ? u1 : (T == 2) ? u2 : u3;

        // ---------- full-wave f32 epilogue ----------
        const float inv1 = f1x * f1x + f1y * f1y + f1z * f1z;
        const float inv2 = f2x * f2x + f2y * f2y + f2z * f2z;
        float s1, s2;
        if (inv1 >= 1e-12f) s1 = g1;
        else {
            const float n1v = inv1 * 1e12f;
            s1 = sb2s;
            for (int o = 0; o < 64; ++o)
                s1 = fmaf(fmaxf(fmaf(n1v, sw1[o], sb1[o]), 0.f), sw2[o], s1);
        }
        if (inv2 >= 1e-12f) s2 = g1;
        else {
            const float n2v = inv2 * 1e12f;
            s2 = sb2s;
            for (int o = 0; o < 64; ++o)
                s2 = fmaf(fmaxf(fmaf(n2v, sw1[o], sb1[o]), 0.f), sw2[o], s2);
        }

        const float xcx = (x1x + x2x) * 0.5f, xcy = (x1y + x2y) * 0.5f, xcz = (x1z + x2z) * 0.5f;
        float vcx = (v1x + v2x) * 0.5f, vcy = (v1y + v2y) * 0.5f, vcz = (v1z + v2z) * 0.5f;
        const float accx = (f1x * s1 + f2x * s2) * 0.5f;
        const float accy = (f1y * s1 + f2y * s2) * 0.5f;
        const float accz = (f1z * s1 + f2z * s2) * 0.5f;

        const float d1x = x1x - xcx, d1y = x1y - xcy, d1z = x1z - xcz;
        const float d2x = x2x - xcx, d2y = x2y - xcy, d2z = x2z - xcz;
        const float inertia = d1x * d1x + d1y * d1y + d1z * d1z
                            + d2x * d2x + d2y * d2y + d2z * d2z;
        const float tqx = (d1y * f1z - d1z * f1y) + (d2y * f2z - d2z * f2y);
        const float tqy = (d1z * f1x - d1x * f1z) + (d2z * f2x - d2x * f2z);
        const float tqz = (d1x * f1y - d1y * f1x) + (d2x * f2y - d2y * f2x);
        const float aax = tqx / inertia, aay = tqy / inertia, aaz = tqz / inertia;

        const float rx = (x1x - x2x) * 0.5f, ry = (x1y - x2y) * 0.5f, rz = (x1z - x2z) * 0.5f;
        const float vrx = (v1x - v2x) * 0.5f, vry = (v1y - v2y) * 0.5f, vrz = (v1z - v2z) * 0.5f;
        const float rn = sqrtf(rx * rx + ry * ry + rz * rz);
        const float rnorm = fmaxf(rn, 1e-5f);
        const float rden = fmaxf(rn, 1e-12f);
        const float rhx = rx / rden, rhy = ry / rden, rhz = rz / rden;
        float wx = (rhy * vrz - rhz * vry) / rnorm;
        float wy = (rhz * vrx - rhx * vrz) / rnorm;
        float wz = (rhx * vry - rhy * vrx) / rnorm;

        vcx = scv * vcx + accx; vcy = scv * vcy + accy; vcz = scv * vcz + accz;
        const float nxcx = xcx + vcx, nxcy = xcy + vcy, nxcz = xcz + vcz;

        wx = sav * wx + aax; wy = sav * wy + aay; wz = sav * wz + aaz;

        const float ang = sqrtf(wx * wx + wy * wy + wz * wz);
        const float dden = fmaxf(ang, 1e-12f);
        const float dx = wx / dden, dy = wy / dden, dz = wz / dden;
        const float cc = cosf(ang), ss = sinf(ang), oc = 1.0f - cc;
        const float r00 = cc + oc * dx * dx,      r01 = oc * dx * dy - ss * dz, r02 = oc * dx * dz + ss * dy;
        const float r10 = oc * dx * dy + ss * dz, r11 = cc + oc * dy * dy,      r12 = oc * dy * dz - ss * dx;
        const float r20 = oc * dx * dz - ss * dy, r21 = oc * dy * dz + ss * dx, r22 = cc + oc * dz * dz;

        const float nrx = r00 * rx + r01 * ry + r02 * rz;
        const float nry = r10 * rx + r11 * ry + r12 * rz;
        const float nrz = r20 * rx + r21 * ry + r22 * rz;

        const float wxrx = wy * nrz - wz * nry;
        const float wxry = wz * nrx - wx * nrz;
        const float wxrz = wx * nry - wy * nrx;

        if (evalid) {
            out_pos[q1 + 0] = nxcx + nrx; out_pos[q1 + 1] = nxcy + nry; out_pos[q1 + 2] = nxcz + nrz;
            out_pos[q2 + 0] = nxcx - nrx; out_pos[q2 + 1] = nxcy - nry; out_pos[q2 + 2] = nxcz - nrz;
            out_vel[q1 + 0] = vcx + wxrx; out_vel[q1 + 1] = vcy + wxry; out_vel[q1 + 2] = vcz + wxrz;
            out_vel[q2 + 0] = vcx - wxrx; out_vel[q2 + 1] = vcy - wxry; out_vel[q2 + 2] = vcz - wxrz;
        }
    } else {
        // ================= iso path =================
        const int macro = (blockIdx.x - nStickBlk) * 4 + w;
        const int nmacro = (I + 63) >> 6;
        if (macro >= nmacro) return;
        const int base = macro << 6;

        const int ne = base + lane;
        const bool evalid = ne < I;
        const int nc = evalid ? ne : (I - 1);
        const int node_e = iso[nc];
        const size_t pe = (size_t)node_e * 3;
        const float px = node_pos[pe], py = node_pos[pe + 1], pz = node_pos[pe + 2];
        const float vx = velocity[pe], vy = velocity[pe + 1], vz = velocity[pe + 2];
        const float fx = force[pe],   fy = force[pe + 1],    fz = force[pe + 2];

        bf16x8 bW[4][2];
        load_wfrags_f32(cvw1, lane, bW);
        float cvb1v[4], cvw2v[4];
        UNROLL for (int nt = 0; nt < 4; ++nt) {
            cvb1v[nt] = cvb1[nt * 16 + n0];
            cvw2v[nt] = cvw2[nt * 16 + n0];
        }
        const float cvb2s = cvb2[0];

        const int r0i = base + n0, r1i = base + 16 + n0;
        const int r2i = base + 32 + n0, r3i = base + 48 + n0;
        const int c0i = (r0i < I) ? r0i : (I - 1), c1i = (r1i < I) ? r1i : (I - 1);
        const int c2i = (r2i < I) ? r2i : (I - 1), c3i = (r3i < I) ? r3i : (I - 1);
        const float* h0 = node_feat + (size_t)iso[c0i] * 64;
        const float* h1 = node_feat + (size_t)iso[c1i] * 64;
        const float* h2 = node_feat + (size_t)iso[c2i] * 64;
        const float* h3 = node_feat + (size_t)iso[c3i] * 64;
        const int o8 = (lane >> 4) << 3;

        v4f r0[4], r1[4], r2[4], r3[4];
        r0[0] = *(const v4f*)(h0 + o8);      r0[1] = *(const v4f*)(h0 + o8 + 4);
        r0[2] = *(const v4f*)(h0 + 32 + o8); r0[3] = *(const v4f*)(h0 + 32 + o8 + 4);
        r1[0] = *(const v4f*)(h1 + o8);      r1[1] = *(const v4f*)(h1 + o8 + 4);
        r1[2] = *(const v4f*)(h1 + 32 + o8); r1[3] = *(const v4f*)(h1 + 32 + o8 + 4);
        const float s0 = iso_tile(r0, lane, bW, cvb1v, cvw2v, cvb2s);
        r2[0] = *(const v4f*)(h2 + o8);      r2[1] = *(const v4f*)(h2 + o8 + 4);
        r2[2] = *(const v4f*)(h2 + 32 + o8); r2[3] = *(const v4f*)(h2 + 32 + o8 + 4);
        const float s1 = iso_tile(r1, lane, bW, cvb1v, cvw2v, cvb2s);
        r3[0] = *(const v4f*)(h3 + o8);      r3[1] = *(const v4f*)(h3 + o8 + 4);
        r3[2] = *(const v4f*)(h3 + 32 + o8); r3[3] = *(const v4f*)(h3 + 32 + o8 + 4);
        const float s2 = iso_tile(r2, lane, bW, cvb1v, cvw2v, cvb2s);
        const float s3 = iso_tile(r3, lane, bW, cvb1v, cvw2v, cvb2s);

        const int T = lane >> 4, r15 = lane & 15;
        const float e0 = __shfl(s0, r15, 64), e1 = __shfl(s1, r15, 64);
        const float e2 = __shfl(s2, r15, 64), e3 = __shfl(s3, r15, 64);
        const float s = (T == 0) ? e0 : (T == 1) ? e1 : (T == 2) ? e2 : e3;

        if (evalid) {
            const float nvx = fmaf(s, vx, fx);
            const float nvy = fmaf(s, vy, fy);
            const float nvz = fmaf(s, vz, fz);
            out_vel[pe + 0] = nvx; out_vel[pe + 1] = nvy; out_vel[pe + 2] = nvz;
            out_pos[pe + 0] = px + nvx; out_pos[pe + 1] = py + nvy; out_pos[pe + 2] = pz + nvz;
        }
    }
}

// ------------------------------ launch -------------------------------------
extern "C" void kernel_launch(void* const* d_in, const int* in_sizes, int n_in,
                              void* d_out, int out_size, void* d_ws, size_t ws_size,
                              hipStream_t stream) {
    const float* node_feat = (const float*)d_in[0];
    const float* node_pos  = (const float*)d_in[1];
    const float* velocity  = (const float*)d_in[2];
    const float* force     = (const float*)d_in[3];
    const int*   iso       = (const int*)d_in[4];
    const int*   stick     = (const int*)d_in[5];
    const float* cvw1 = (const float*)d_in[6];  const float* cvb1 = (const float*)d_in[7];
    const float* cvw2 = (const float*)d_in[8];  const float* cvb2 = (const float*)d_in[9];
    const float* avw1 = (const float*)d_in[10]; const float* avb1 = (const float*)d_in[11];
    const float* avw2 = (const float*)d_in[12]; const float* avb2 = (const float*)d_in[13];
    const float* cw1  = (const float*)d_in[14]; const float* cb1  = (const float*)d_in[15];
    const float* cw2  = (const float*)d_in[16]; const float* cb2  = (const float*)d_in[17];
    const float* sw1  = (const float*)d_in[18]; const float* sb1  = (const float*)d_in[19];
    const float* sw2  = (const float*)d_in[20]; const float* sb2  = (const float*)d_in[21];

    const int N = in_sizes[1] / 3;
    const int I = in_sizes[4];
    const int K = in_sizes[5] / 2;

    float* out_pos = (float*)d_out;
    float* out_vel = out_pos + (size_t)N * 3;

    // Base copy only if the index sets cannot cover all nodes.
    if ((long long)I + 2LL * (long long)K < (long long)N) {
        hipMemcpyAsync(out_pos, node_pos, sizeof(float) * (size_t)N * 3,
                       hipMemcpyDeviceToDevice, stream);
        hipMemcpyAsync(out_vel, velocity, sizeof(float) * (size_t)N * 3,
                       hipMemcpyDeviceToDevice, stream);
    }

    const int nmacroS = (K + 63) / 64;
    const int nmacroI = (I + 63) / 64;
    const int nStickBlk = (nmacroS + 3) / 4;
    const int nIsoBlk = (nmacroI + 3) / 4;
    const int grid = nStickBlk + nIsoBlk;
    if (grid > 0) {
        fused_kernel<<<grid, 256, 0, stream>>>(
            node_feat, node_pos, velocity, force, iso, stick,
            cvw1, cvb1, cvw2, cvb2, avw1, avb1, avw2, avb2,
            cw1, cb1, cw2, cb2, sw1, sb1, sw2, sb2,
            out_pos, out_vel, I, K, nStickBlk);
    }
}

// Round 10
// 70.541 us; speedup vs baseline: 1.0926x; 1.0926x over previous
//
#include <hip/hip_runtime.h>

// ---------------------------------------------------------------------------
// GMNLayer round 10: round-8 structure (prep kernel + packed bf16 weight
// frags in d_ws; 3-phase stick wave; full-wave epilogue) with latency-order
// fixes: HBM raw loads issued before L2 weight loads, epilogue gathers
// hoisted to phase-2 start.
// ---------------------------------------------------------------------------

typedef __bf16 bf16x8 __attribute__((ext_vector_type(8)));
typedef float f32x4 __attribute__((ext_vector_type(4)));
typedef float v4f __attribute__((ext_vector_type(4)));

#define UNROLL _Pragma("unroll")

__device__ __forceinline__ bf16x8 cvt_frag(v4f lo, v4f hi) {
    bf16x8 f;
    UNROLL for (int j = 0; j < 4; ++j) { f[j] = (__bf16)lo[j]; f[j + 4] = (__bf16)hi[j]; }
    return f;
}

// ------------------------------ prep kernel --------------------------------
// ws: 32 frag-sets (m*8 + nt*2 + kb) x 64 lanes x 8 bf16 (32 KB).
// m: 0=cw1, 1=cw2, 2=cvw1, 3=avw1.  At 64KB: float g1.
__global__ __launch_bounds__(64) void prep_kernel(
    const float* __restrict__ cw1, const float* __restrict__ cw2,
    const float* __restrict__ cvw1, const float* __restrict__ avw1,
    const float* __restrict__ sw1, const float* __restrict__ sb1,
    const float* __restrict__ sw2, const float* __restrict__ sb2,
    __bf16* __restrict__ wf, float* __restrict__ extra)
{
    const int fs = blockIdx.x;
    const int lane = threadIdx.x;
    const int m = fs >> 3, rr = fs & 7, nt = rr >> 1, kb = rr & 1;
    const float* W = (m == 0) ? cw1 : (m == 1) ? cw2 : (m == 2) ? cvw1 : avw1;
    const int n0 = lane & 15;
    const int k0 = kb * 32 + ((lane >> 4) << 3);
    __bf16* dst = wf + ((size_t)fs * 64 + lane) * 8;
    UNROLL for (int j = 0; j < 8; ++j)
        dst[j] = (__bf16)W[(k0 + j) * 64 + nt * 16 + n0];
    if (fs == 0 && lane == 0) {
        float g1 = sb2[0];
        for (int o = 0; o < 64; ++o)
            g1 = fmaf(fmaxf(sw1[o] + sb1[o], 0.f), sw2[o], g1);
        extra[0] = g1;
    }
}

__device__ __forceinline__ void load_wfrags(const __bf16* __restrict__ wf, int m,
                                            int lane, bf16x8 out[4][2]) {
    UNROLL for (int nt = 0; nt < 4; ++nt)
        UNROLL for (int kb = 0; kb < 2; ++kb)
            out[nt][kb] = *(const bf16x8*)(wf + ((size_t)((m * 8 + nt * 2 + kb) * 64 + lane)) * 8);
}

__device__ __forceinline__ void load_raw(v4f r[8], const float* h1p, const float* h2p, int lane) {
    const int o8 = (lane >> 4) << 3;
    r[0] = *(const v4f*)(h1p + o8);      r[1] = *(const v4f*)(h1p + o8 + 4);
    r[2] = *(const v4f*)(h1p + 32 + o8); r[3] = *(const v4f*)(h1p + 32 + o8 + 4);
    r[4] = *(const v4f*)(h2p + o8);      r[5] = *(const v4f*)(h2p + o8 + 4);
    r[6] = *(const v4f*)(h2p + 32 + o8); r[7] = *(const v4f*)(h2p + 32 + o8 + 4);
}

// ---- phase helpers (per-wave LDS tile buffers, no block barrier) ----
__device__ __forceinline__ void l1_tile(const v4f raw[8], int lane,
                                        const bf16x8 bW[4][2], const float cb1v[4],
                                        __bf16* srow)
{
    const int n0 = lane & 15;
    const int g4 = (lane >> 4) << 2;
    bf16x8 a1[2], a2[2];
    a1[0] = cvt_frag(raw[0], raw[1]); a1[1] = cvt_frag(raw[2], raw[3]);
    a2[0] = cvt_frag(raw[4], raw[5]); a2[1] = cvt_frag(raw[6], raw[7]);
    UNROLL for (int nt = 0; nt < 4; ++nt) {
        f32x4 cA = {0.f, 0.f, 0.f, 0.f}, cB = {0.f, 0.f, 0.f, 0.f};
        UNROLL for (int kb = 0; kb < 2; ++kb) {
            cA = __builtin_amdgcn_mfma_f32_16x16x32_bf16(a1[kb], bW[nt][kb], cA, 0, 0, 0);
            cB = __builtin_amdgcn_mfma_f32_16x16x32_bf16(a2[kb], bW[nt][kb], cB, 0, 0, 0);
        }
        UNROLL for (int q = 0; q < 4; ++q) {
            const float v = fmaxf(cA[q] + cb1v[nt], 0.f) + fmaxf(cB[q] + cb1v[nt], 0.f);
            srow[(g4 + q) * 72 + nt * 16 + n0] = (__bf16)v;
        }
    }
}

__device__ __forceinline__ void l2_tile(int lane, const bf16x8 bW[4][2],
                                        const float cb2v[4], __bf16* srow)
{
    const int n0 = lane & 15;
    const int g4 = (lane >> 4) << 2;
    const int kb8 = (lane >> 4) << 3;
    bf16x8 sA[2];
    UNROLL for (int kb = 0; kb < 2; ++kb)
        sA[kb] = *(const bf16x8*)&srow[n0 * 72 + kb * 32 + kb8];
    UNROLL for (int nt = 0; nt < 4; ++nt) {
        f32x4 c = {0.f, 0.f, 0.f, 0.f};
        UNROLL for (int kb = 0; kb < 2; ++kb)
            c = __builtin_amdgcn_mfma_f32_16x16x32_bf16(sA[kb], bW[nt][kb], c, 0, 0, 0);
        UNROLL for (int q = 0; q < 4; ++q)
            srow[(g4 + q) * 72 + nt * 16 + n0] = (__bf16)(c[q] + cb2v[nt]);
    }
}

__device__ __forceinline__ void cvav_tile(int lane,
                                          const bf16x8 bCV[4][2], const bf16x8 bAV[4][2],
                                          const float cvb1v[4], const float avb1v[4],
                                          const float cvw2v[4], const float avw2v[4],
                                          float cvb2s, float avb2s,
                                          const __bf16* srow, float& scv, float& sav)
{
    const int n0 = lane & 15;
    const int kb8 = (lane >> 4) << 3;
    bf16x8 hA[2];
    UNROLL for (int kb = 0; kb < 2; ++kb)
        hA[kb] = *(const bf16x8*)&srow[n0 * 72 + kb * 32 + kb8];
    float pc[4] = {0.f, 0.f, 0.f, 0.f}, pa[4] = {0.f, 0.f, 0.f, 0.f};
    UNROLL for (int nt = 0; nt < 4; ++nt) {
        f32x4 cv = {0.f, 0.f, 0.f, 0.f}, av = {0.f, 0.f, 0.f, 0.f};
        UNROLL for (int kb = 0; kb < 2; ++kb) {
            cv = __builtin_amdgcn_mfma_f32_16x16x32_bf16(hA[kb], bCV[nt][kb], cv, 0, 0, 0);
            av = __builtin_amdgcn_mfma_f32_16x16x32_bf16(hA[kb], bAV[nt][kb], av, 0, 0, 0);
        }
        UNROLL for (int q = 0; q < 4; ++q) {
            pc[q] = fmaf(fmaxf(cv[q] + cvb1v[nt], 0.f), cvw2v[nt], pc[q]);
            pa[q] = fmaf(fmaxf(av[q] + avb1v[nt], 0.f), avw2v[nt], pa[q]);
        }
    }
    UNROLL for (int q = 0; q < 4; ++q)
        UNROLL for (int off = 1; off < 16; off <<= 1) {
            pc[q] += __shfl_xor(pc[q], off, 64);
            pa[q] += __shfl_xor(pa[q], off, 64);
        }
    const int srcl = ((lane & 15) >> 2) << 4;
    const float c0 = __shfl(pc[0], srcl, 64), c1 = __shfl(pc[1], srcl, 64);
    const float c2 = __shfl(pc[2], srcl, 64), c3 = __shfl(pc[3], srcl, 64);
    const float b0 = __shfl(pa[0], srcl, 64), b1 = __shfl(pa[1], srcl, 64);
    const float b2 = __shfl(pa[2], srcl, 64), b3 = __shfl(pa[3], srcl, 64);
    const int qq = lane & 3;
    scv = (qq == 0 ? c0 : qq == 1 ? c1 : qq == 2 ? c2 : c3) + cvb2s;
    sav = (qq == 0 ? b0 : qq == 1 ? b1 : qq == 2 ? b2 : b3) + avb2s;
}

// iso 16-node tile
__device__ __forceinline__ float iso_tile(
    const v4f raw[4], int lane, const bf16x8 bW[4][2],
    const float cvb1v[4], const float cvw2v[4], float cvb2s)
{
    bf16x8 a[2];
    a[0] = cvt_frag(raw[0], raw[1]);
    a[1] = cvt_frag(raw[2], raw[3]);
    float p[4] = {0.f, 0.f, 0.f, 0.f};
    UNROLL for (int nt = 0; nt < 4; ++nt) {
        f32x4 c = {0.f, 0.f, 0.f, 0.f};
        UNROLL for (int kb = 0; kb < 2; ++kb)
            c = __builtin_amdgcn_mfma_f32_16x16x32_bf16(a[kb], bW[nt][kb], c, 0, 0, 0);
        UNROLL for (int q = 0; q < 4; ++q)
            p[q] = fmaf(fmaxf(c[q] + cvb1v[nt], 0.f), cvw2v[nt], p[q]);
    }
    UNROLL for (int q = 0; q < 4; ++q)
        UNROLL for (int off = 1; off < 16; off <<= 1)
            p[q] += __shfl_xor(p[q], off, 64);
    const int srcl = ((lane & 15) >> 2) << 4;
    const float t0 = __shfl(p[0], srcl, 64), t1 = __shfl(p[1], srcl, 64);
    const float t2 = __shfl(p[2], srcl, 64), t3 = __shfl(p[3], srcl, 64);
    const int qq = lane & 3;
    return (qq == 0 ? t0 : qq == 1 ? t1 : qq == 2 ? t2 : t3) + cvb2s;
}

// ------------------------------ fused kernel -------------------------------
__global__ __launch_bounds__(256, 2) void fused_kernel(
    const float* __restrict__ node_feat, const float* __restrict__ node_pos,
    const float* __restrict__ velocity, const float* __restrict__ force,
    const int* __restrict__ iso, const int* __restrict__ stick,
    const __bf16* __restrict__ wf, const float* __restrict__ extra,
    const float* __restrict__ cvb1, const float* __restrict__ cvw2,
    const float* __restrict__ cvb2,
    const float* __restrict__ avb1, const float* __restrict__ avw2,
    const float* __restrict__ avb2,
    const float* __restrict__ cb1,  const float* __restrict__ cb2,
    const float* __restrict__ sw1,  const float* __restrict__ sb1,
    const float* __restrict__ sw2,  const float* __restrict__ sb2,
    float* __restrict__ out_pos, float* __restrict__ out_vel,
    int I, int K, int nStickBlk)
{
    __shared__ __align__(16) __bf16 sbuf[4][4][16 * 72];  // [wave][tile][16x72]
    const int lane = threadIdx.x & 63;
    const int w = threadIdx.x >> 6;
    const int n0 = lane & 15;

    if (blockIdx.x < (unsigned)nStickBlk) {
        // ================= stick path (3-phase) =================
        const int macro = blockIdx.x * 4 + w;
        const int nmacro = (K + 63) >> 6;
        if (macro >= nmacro) return;
        const int base = macro << 6;

        // tile indices (clamped)
        const int s0i = base + n0, s1i = base + 16 + n0;
        const int s2i = base + 32 + n0, s3i = base + 48 + n0;
        const int a0 = (s0i < K) ? s0i : (K - 1), a1i = (s1i < K) ? s1i : (K - 1);
        const int a2i = (s2i < K) ? s2i : (K - 1), a3 = (s3i < K) ? s3i : (K - 1);
        const int t0i1 = stick[a0],  t0i2 = stick[K + a0];
        const int t1i1 = stick[a1i], t1i2 = stick[K + a1i];
        const int t2i1 = stick[a2i], t2i2 = stick[K + a2i];
        const int t3i1 = stick[a3],  t3i2 = stick[K + a3];

        __bf16* srow0 = &sbuf[w][0][0];
        __bf16* srow1 = &sbuf[w][1][0];
        __bf16* srow2 = &sbuf[w][2][0];
        __bf16* srow3 = &sbuf[w][3][0];

        bf16x8 bW[4][2], bW2[4][2];

        // ---------- phase 1: HBM raw loads FIRST, then L2 weight frags ----
        v4f rA[8], rB[8];
        load_raw(rA, node_feat + (size_t)t0i1 * 64, node_feat + (size_t)t0i2 * 64, lane);
        load_raw(rB, node_feat + (size_t)t1i1 * 64, node_feat + (size_t)t1i2 * 64, lane);

        float cb1v[4];
        UNROLL for (int nt = 0; nt < 4; ++nt) cb1v[nt] = cb1[nt * 16 + n0];
        load_wfrags(wf, 0, lane, bW);

        l1_tile(rA, lane, bW, cb1v, srow0);
        load_raw(rA, node_feat + (size_t)t2i1 * 64, node_feat + (size_t)t2i2 * 64, lane);
        l1_tile(rB, lane, bW, cb1v, srow1);
        load_raw(rB, node_feat + (size_t)t3i1 * 64, node_feat + (size_t)t3i2 * 64, lane);
        l1_tile(rA, lane, bW, cb1v, srow2);
        l1_tile(rB, lane, bW, cb1v, srow3);

        // ---------- epilogue gathers issued here (hide under phases 2-3) ---
        const int ke = base + lane;
        const bool evalid = ke < K;
        const int kc = evalid ? ke : (K - 1);
        const int i1e = stick[kc];
        const int i2e = stick[K + kc];
        const size_t q1 = (size_t)i1e * 3, q2 = (size_t)i2e * 3;
        const float x1x = node_pos[q1], x1y = node_pos[q1 + 1], x1z = node_pos[q1 + 2];
        const float x2x = node_pos[q2], x2y = node_pos[q2 + 1], x2z = node_pos[q2 + 2];
        const float v1x = velocity[q1], v1y = velocity[q1 + 1], v1z = velocity[q1 + 2];
        const float v2x = velocity[q2], v2y = velocity[q2 + 1], v2z = velocity[q2 + 2];
        const float f1x = force[q1],   f1y = force[q1 + 1],   f1z = force[q1 + 2];
        const float f2x = force[q2],   f2y = force[q2 + 1],   f2z = force[q2 + 2];

        // ---------- phase 2: layer-2 for 4 tiles (only cw2 live) ----------
        float cb2v[4];
        UNROLL for (int nt = 0; nt < 4; ++nt) cb2v[nt] = 2.0f * cb2[nt * 16 + n0];
        load_wfrags(wf, 1, lane, bW);
        l2_tile(lane, bW, cb2v, srow0);
        l2_tile(lane, bW, cb2v, srow1);
        l2_tile(lane, bW, cb2v, srow2);
        l2_tile(lane, bW, cb2v, srow3);

        // ---------- phase 3: cv/av for 4 tiles ----------
        float cvb1v[4], avb1v[4], cvw2v[4], avw2v[4];
        UNROLL for (int nt = 0; nt < 4; ++nt) {
            const int c = nt * 16 + n0;
            cvb1v[nt] = cvb1[c];
            avb1v[nt] = avb1[c];
            cvw2v[nt] = cvw2[c];
            avw2v[nt] = avw2[c];
        }
        const float cvb2s = cvb2[0], avb2s = avb2[0], sb2s = sb2[0];
        const float g1 = extra[0];

        load_wfrags(wf, 2, lane, bW);    // cvw1
        load_wfrags(wf, 3, lane, bW2);   // avw1
        float scv0, sav0, scv1, sav1, scv2, sav2, scv3, sav3;
        cvav_tile(lane, bW, bW2, cvb1v, avb1v, cvw2v, avw2v, cvb2s, avb2s, srow0, scv0, sav0);
        cvav_tile(lane, bW, bW2, cvb1v, avb1v, cvw2v, avw2v, cvb2s, avb2s, srow1, scv1, sav1);
        cvav_tile(lane, bW, bW2, cvb1v, avb1v, cvw2v, avw2v, cvb2s, avb2s, srow2, scv2, sav2);
        cvav_tile(lane, bW, bW2, cvb1v, avb1v, cvw2v, avw2v, cvb2s, avb2s, srow3, scv3, sav3);

        // redistribute scv/sav to stick-owning lane (stick = base + lane)
        const int T = lane >> 4, r15 = lane & 15;
        const float e0 = __shfl(scv0, r15, 64), e1 = __shfl(scv1, r15, 64);
        const float e2 = __shfl(scv2, r15, 64), e3 = __shfl(scv3, r15, 64);
        const float u0 = __shfl(sav0, r15, 64), u1 = __shfl(sav1, r15, 64);
        const float u2 = __shfl(sav2, r15, 64), u3 = __shfl(sav3, r15, 64);
        const float scv = (T == 0) ? e0 : (T == 1) ? e1 : (T == 2) ? e2 : e3;
        const float sav = (T == 0) ? u0 : (T == 1) ? u1 : (T == 2) ? u2 : u3;

        // ---------- full-wave f32 epilogue ----------
        const float inv1 = f1x * f1x + f1y * f1y + f1z * f1z;
        const float inv2 = f2x * f2x + f2y * f2y + f2z * f2z;
        float s1, s2;
        if (inv1 >= 1e-12f) s1 = g1;
        else {
            const float n1v = inv1 * 1e12f;
            s1 = sb2s;
            for (int o = 0; o < 64; ++o)
                s1 = fmaf(fmaxf(fmaf(n1v, sw1[o], sb1[o]), 0.f), sw2[o], s1);
        }
        if (inv2 >= 1e-12f) s2 = g1;
        else {
            const float n2v = inv2 * 1e12f;
            s2 = sb2s;
            for (int o = 0; o < 64; ++o)
                s2 = fmaf(fmaxf(fmaf(n2v, sw1[o], sb1[o]), 0.f), sw2[o], s2);
        }

        const float xcx = (x1x + x2x) * 0.5f, xcy = (x1y + x2y) * 0.5f, xcz = (x1z + x2z) * 0.5f;
        float vcx = (v1x + v2x) * 0.5f, vcy = (v1y + v2y) * 0.5f, vcz = (v1z + v2z) * 0.5f;
        const float accx = (f1x * s1 + f2x * s2) * 0.5f;
        const float accy = (f1y * s1 + f2y * s2) * 0.5f;
        const float accz = (f1z * s1 + f2z * s2) * 0.5f;

        const float d1x = x1x - xcx, d1y = x1y - xcy, d1z = x1z - xcz;
        const float d2x = x2x - xcx, d2y = x2y - xcy, d2z = x2z - xcz;
        const float inertia = d1x * d1x + d1y * d1y + d1z * d1z
                            + d2x * d2x + d2y * d2y + d2z * d2z;
        const float tqx = (d1y * f1z - d1z * f1y) + (d2y * f2z - d2z * f2y);
        const float tqy = (d1z * f1x - d1x * f1z) + (d2z * f2x - d2x * f2z);
        const float tqz = (d1x * f1y - d1y * f1x) + (d2x * f2y - d2y * f2x);
        const float aax = tqx / inertia, aay = tqy / inertia, aaz = tqz / inertia;

        const float rx = (x1x - x2x) * 0.5f, ry = (x1y - x2y) * 0.5f, rz = (x1z - x2z) * 0.5f;
        const float vrx = (v1x - v2x) * 0.5f, vry = (v1y - v2y) * 0.5f, vrz = (v1z - v2z) * 0.5f;
        const float rn = sqrtf(rx * rx + ry * ry + rz * rz);
        const float rnorm = fmaxf(rn, 1e-5f);
        const float rden = fmaxf(rn, 1e-12f);
        const float rhx = rx / rden, rhy = ry / rden, rhz = rz / rden;
        float wx = (rhy * vrz - rhz * vry) / rnorm;
        float wy = (rhz * vrx - rhx * vrz) / rnorm;
        float wz = (rhx * vry - rhy * vrx) / rnorm;

        vcx = scv * vcx + accx; vcy = scv * vcy + accy; vcz = scv * vcz + accz;
        const float nxcx = xcx + vcx, nxcy = xcy + vcy, nxcz = xcz + vcz;

        wx = sav * wx + aax; wy = sav * wy + aay; wz = sav * wz + aaz;

        const float ang = sqrtf(wx * wx + wy * wy + wz * wz);
        const float dden = fmaxf(ang, 1e-12f);
        const float dx = wx / dden, dy = wy / dden, dz = wz / dden;
        const float cc = cosf(ang), ss = sinf(ang), oc = 1.0f - cc;
        const float r00 = cc + oc * dx * dx,      r01 = oc * dx * dy - ss * dz, r02 = oc * dx * dz + ss * dy;
        const float r10 = oc * dx * dy + ss * dz, r11 = cc + oc * dy * dy,      r12 = oc * dy * dz - ss * dx;
        const float r20 = oc * dx * dz - ss * dy, r21 = oc * dy * dz + ss * dx, r22 = cc + oc * dz * dz;

        const float nrx = r00 * rx + r01 * ry + r02 * rz;
        const float nry = r10 * rx + r11 * ry + r12 * rz;
        const float nrz = r20 * rx + r21 * ry + r22 * rz;

        const float wxrx = wy * nrz - wz * nry;
        const float wxry = wz * nrx - wx * nrz;
        const float wxrz = wx * nry - wy * nrx;

        if (evalid) {
            out_pos[q1 + 0] = nxcx + nrx; out_pos[q1 + 1] = nxcy + nry; out_pos[q1 + 2] = nxcz + nrz;
            out_pos[q2 + 0] = nxcx - nrx; out_pos[q2 + 1] = nxcy - nry; out_pos[q2 + 2] = nxcz - nrz;
            out_vel[q1 + 0] = vcx + wxrx; out_vel[q1 + 1] = vcy + wxry; out_vel[q1 + 2] = vcz + wxrz;
            out_vel[q2 + 0] = vcx - wxrx; out_vel[q2 + 1] = vcy - wxry; out_vel[q2 + 2] = vcz - wxrz;
        }
    } else {
        // ================= iso path =================
        const int macro = (blockIdx.x - nStickBlk) * 4 + w;
        const int nmacro = (I + 63) >> 6;
        if (macro >= nmacro) return;
        const int base = macro << 6;

        const int ne = base + lane;
        const bool evalid = ne < I;
        const int nc = evalid ? ne : (I - 1);
        const int node_e = iso[nc];
        const size_t pe = (size_t)node_e * 3;
        const float px = node_pos[pe], py = node_pos[pe + 1], pz = node_pos[pe + 2];
        const float vx = velocity[pe], vy = velocity[pe + 1], vz = velocity[pe + 2];
        const float fx = force[pe],   fy = force[pe + 1],    fz = force[pe + 2];

        const int r0i = base + n0, r1i = base + 16 + n0;
        const int r2i = base + 32 + n0, r3i = base + 48 + n0;
        const int c0i = (r0i < I) ? r0i : (I - 1), c1i = (r1i < I) ? r1i : (I - 1);
        const int c2i = (r2i < I) ? r2i : (I - 1), c3i = (r3i < I) ? r3i : (I - 1);
        const float* h0 = node_feat + (size_t)iso[c0i] * 64;
        const float* h1 = node_feat + (size_t)iso[c1i] * 64;
        const float* h2 = node_feat + (size_t)iso[c2i] * 64;
        const float* h3 = node_feat + (size_t)iso[c3i] * 64;
        const int o8 = (lane >> 4) << 3;

        v4f r0[4], r1[4], r2[4], r3[4];
        r0[0] = *(const v4f*)(h0 + o8);      r0[1] = *(const v4f*)(h0 + o8 + 4);
        r0[2] = *(const v4f*)(h0 + 32 + o8); r0[3] = *(const v4f*)(h0 + 32 + o8 + 4);
        r1[0] = *(const v4f*)(h1 + o8);      r1[1] = *(const v4f*)(h1 + o8 + 4);
        r1[2] = *(const v4f*)(h1 + 32 + o8); r1[3] = *(const v4f*)(h1 + 32 + o8 + 4);

        bf16x8 bW[4][2];
        load_wfrags(wf, 2, lane, bW);
        float cvb1v[4], cvw2v[4];
        UNROLL for (int nt = 0; nt < 4; ++nt) {
            cvb1v[nt] = cvb1[nt * 16 + n0];
            cvw2v[nt] = cvw2[nt * 16 + n0];
        }
        const float cvb2s = cvb2[0];

        const float s0 = iso_tile(r0, lane, bW, cvb1v, cvw2v, cvb2s);
        r2[0] = *(const v4f*)(h2 + o8);      r2[1] = *(const v4f*)(h2 + o8 + 4);
        r2[2] = *(const v4f*)(h2 + 32 + o8); r2[3] = *(const v4f*)(h2 + 32 + o8 + 4);
        const float s1 = iso_tile(r1, lane, bW, cvb1v, cvw2v, cvb2s);
        r3[0] = *(const v4f*)(h3 + o8);      r3[1] = *(const v4f*)(h3 + o8 + 4);
        r3[2] = *(const v4f*)(h3 + 32 + o8); r3[3] = *(const v4f*)(h3 + 32 + o8 + 4);
        const float s2 = iso_tile(r2, lane, bW, cvb1v, cvw2v, cvb2s);
        const float s3 = iso_tile(r3, lane, bW, cvb1v, cvw2v, cvb2s);

        const int T = lane >> 4, r15 = lane & 15;
        const float e0 = __shfl(s0, r15, 64), e1 = __shfl(s1, r15, 64);
        const float e2 = __shfl(s2, r15, 64), e3 = __shfl(s3, r15, 64);
        const float s = (T == 0) ? e0 : (T == 1) ? e1 : (T == 2) ? e2 : e3;

        if (evalid) {
            const float nvx = fmaf(s, vx, fx);
            const float nvy = fmaf(s, vy, fy);
            const float nvz = fmaf(s, vz, fz);
            out_vel[pe + 0] = nvx; out_vel[pe + 1] = nvy; out_vel[pe + 2] = nvz;
            out_pos[pe + 0] = px + nvx; out_pos[pe + 1] = py + nvy; out_pos[pe + 2] = pz + nvz;
        }
    }
}

// ------------------------------ launch -------------------------------------
extern "C" void kernel_launch(void* const* d_in, const int* in_sizes, int n_in,
                              void* d_out, int out_size, void* d_ws, size_t ws_size,
                              hipStream_t stream) {
    const float* node_feat = (const float*)d_in[0];
    const float* node_pos  = (const float*)d_in[1];
    const float* velocity  = (const float*)d_in[2];
    const float* force     = (const float*)d_in[3];
    const int*   iso       = (const int*)d_in[4];
    const int*   stick     = (const int*)d_in[5];
    const float* cvw1 = (const float*)d_in[6];  const float* cvb1 = (const float*)d_in[7];
    const float* cvw2 = (const float*)d_in[8];  const float* cvb2 = (const float*)d_in[9];
    const float* avw1 = (const float*)d_in[10]; const float* avb1 = (const float*)d_in[11];
    const float* avw2 = (const float*)d_in[12]; const float* avb2 = (const float*)d_in[13];
    const float* cw1  = (const float*)d_in[14]; const float* cb1  = (const float*)d_in[15];
    const float* cw2  = (const float*)d_in[16]; const float* cb2  = (const float*)d_in[17];
    const float* sw1  = (const float*)d_in[18]; const float* sb1  = (const float*)d_in[19];
    const float* sw2  = (const float*)d_in[20]; const float* sb2  = (const float*)d_in[21];

    const int N = in_sizes[1] / 3;
    const int I = in_sizes[4];
    const int K = in_sizes[5] / 2;

    float* out_pos = (float*)d_out;
    float* out_vel = out_pos + (size_t)N * 3;

    __bf16* wf = (__bf16*)d_ws;
    float* extra = (float*)((char*)d_ws + 65536);

    // Base copy only if the index sets cannot cover all nodes.
    if ((long long)I + 2LL * (long long)K < (long long)N) {
        hipMemcpyAsync(out_pos, node_pos, sizeof(float) * (size_t)N * 3,
                       hipMemcpyDeviceToDevice, stream);
        hipMemcpyAsync(out_vel, velocity, sizeof(float) * (size_t)N * 3,
                       hipMemcpyDeviceToDevice, stream);
    }

    prep_kernel<<<32, 64, 0, stream>>>(cw1, cw2, cvw1, avw1, sw1, sb1, sw2, sb2,
                                       wf, extra);

    const int nmacroS = (K + 63) / 64;
    const int nmacroI = (I + 63) / 64;
    const int nStickBlk = (nmacroS + 3) / 4;
    const int nIsoBlk = (nmacroI + 3) / 4;
    const int grid = nStickBlk + nIsoBlk;
    if (grid > 0) {
        fused_kernel<<<grid, 256, 0, stream>>>(
            node_feat, node_pos, velocity, force, iso, stick, wf, extra,
            cvb1, cvw2, cvb2, avb1, avw2, avb2, cb1, cb2,
            sw1, sb1, sw2, sb2, out_pos, out_vel, I, K, nStickBlk);
    }
}